// Round 10
// baseline (84.851 us; speedup 1.0000x reference)
//
#include <hip/hip_runtime.h>
#include <math.h>

#define NN   65536
#define DEGC 16
#define DD   64
#define DD2  128
#define BB   1024
#define NEGC 10
#define NROWS (2 * BB + NEGC)      // 2058
#define NEDGE (NROWS * DEGC)       // 32928
#define MAXU  33024

__device__ __forceinline__ float tanh_fast(float x) {
    float t = __expf(2.0f * x);
    return 1.0f - 2.0f * __builtin_amdgcn_rcpf(t + 1.0f);
}

// ---------------------------------------------------------------------------
// K0: mark + compact unique hop-1 nodes; flags[n] = pos+1 in list.  (R2-proven)
// ---------------------------------------------------------------------------
__global__ __launch_bounds__(256) void mark_compact_kernel(
    const int* __restrict__ adj,
    const int* __restrict__ in1, const int* __restrict__ in2,
    const int* __restrict__ neg,
    int* __restrict__ flags, int* __restrict__ list, int* __restrict__ count) {

    int e = blockIdx.x * 256 + threadIdx.x;
    int nbr = 0;
    bool isnew = false;
    if (e < NEDGE) {
        int r = e >> 4, k = e & 15;
        int node = (r < BB) ? in1[r] : (r < 2 * BB ? in2[r - BB] : neg[r - 2 * BB]);
        nbr = adj[node * DEGC + k];
        int old = atomicCAS(&flags[nbr], 0, 1);
        isnew = (old == 0);
    }
    unsigned long long mask = __ballot(isnew);
    if (mask) {
        int lane = threadIdx.x & 63;
        int cnt = __popcll(mask);
        int leader = __ffsll((long long)mask) - 1;
        int base = 0;
        if (lane == leader) base = atomicAdd(count, cnt);
        base = __shfl(base, leader, 64);
        if (isnew) {
            int pos = base + __popcll(mask & ((1ull << lane) - 1));
            list[pos] = nbr;
            flags[nbr] = pos + 1;
        }
    }
}

// ---------------------------------------------------------------------------
// K1: dense index-free GEMM: Q[n][j] = sum_i feat[n][i] * W1[j][64+i]
// R9-gemv1's proven register shape (4 consecutive nodes/wave, W1b float4-tiled
// in 16KB LDS, c-operands via uniform-address broadcast loads).
// ---------------------------------------------------------------------------
__global__ __launch_bounds__(256) void qgemm_kernel(
    const float* __restrict__ feat, const float* __restrict__ W1,
    float* __restrict__ Q) {

    __shared__ float4 qb[1024];           // 16 KB: qb[(i4<<6)|j] = W1[j][64+4i4..]
    int tid = threadIdx.x;
    {
        int j = tid & 63, g = tid >> 6;
        #pragma unroll
        for (int t = 0; t < 4; ++t) {
            int i4 = g * 4 + t;
            qb[(i4 << 6) | j] = *(const float4*)(W1 + j * DD2 + DD + i4 * 4);
        }
    }
    __syncthreads();

    int lane = tid & 63;
    int w = tid >> 6;
    int nbase = __builtin_amdgcn_readfirstlane((blockIdx.x * 4 + w) * 4);

    const float* f0 = feat + (size_t)(nbase + 0) * DD;
    const float* f1 = feat + (size_t)(nbase + 1) * DD;
    const float* f2 = feat + (size_t)(nbase + 2) * DD;
    const float* f3 = feat + (size_t)(nbase + 3) * DD;

    float a0 = 0.f, a1 = 0.f, a2 = 0.f, a3 = 0.f;
    #pragma unroll
    for (int i4 = 0; i4 < 16; ++i4) {
        float4 wv = qb[(i4 << 6) | lane];          // ds_read_b128
        float4 c0 = *(const float4*)(f0 + i4 * 4); // uniform -> broadcast
        float4 c1 = *(const float4*)(f1 + i4 * 4);
        float4 c2 = *(const float4*)(f2 + i4 * 4);
        float4 c3 = *(const float4*)(f3 + i4 * 4);
        a0 += c0.x * wv.x + c0.y * wv.y + c0.z * wv.z + c0.w * wv.w;
        a1 += c1.x * wv.x + c1.y * wv.y + c1.z * wv.z + c1.w * wv.w;
        a2 += c2.x * wv.x + c2.y * wv.y + c2.z * wv.z + c2.w * wv.w;
        a3 += c3.x * wv.x + c3.y * wv.y + c3.z * wv.z + c3.w * wv.w;
    }
    Q[(size_t)(nbase + 0) * DD + lane] = a0;
    Q[(size_t)(nbase + 1) * DD + lane] = a1;
    Q[(size_t)(nbase + 2) * DD + lane] = a2;
    Q[(size_t)(nbase + 3) * DD + lane] = a3;
}

// ---------------------------------------------------------------------------
// K2: per unique node a (n=list[a]): h1[a] = tanh(P(n) + sum_k Q[adj[n][k]] + b1)
// Pure gather of 16 Q-rows (the irreducible scattered traffic) + inline P(n)
// GEMV (16KB LDS W1a, uniform-broadcast feat row) that overlaps gather latency.
// ---------------------------------------------------------------------------
__global__ __launch_bounds__(256) void gatherh1_kernel(
    const float* __restrict__ feat, const float* __restrict__ Q,
    const int* __restrict__ adj, const int* __restrict__ list,
    const int* __restrict__ count_p,
    const float* __restrict__ W1, const float* __restrict__ b1,
    float* __restrict__ h1) {

    __shared__ float4 qa[1024];           // 16 KB: qa[(i4<<6)|j] = W1[j][4i4..]
    int tid = threadIdx.x;
    {
        int j = tid & 63, g = tid >> 6;
        #pragma unroll
        for (int t = 0; t < 4; ++t) {
            int i4 = g * 4 + t;
            qa[(i4 << 6) | j] = *(const float4*)(W1 + j * DD2 + i4 * 4);
        }
    }
    __syncthreads();

    int lane = tid & 63;
    int wid = blockIdx.x * 4 + (tid >> 6);
    int nw = gridDim.x * 4;
    int count = __builtin_amdgcn_readfirstlane(*count_p);
    float bias = b1[lane];

    for (int a = wid; a < count; a += nw) {
        int n = __builtin_amdgcn_readfirstlane(list[a]);
        const int* arow = adj + n * DEGC;          // uniform -> s_load
        // 16 scattered Q-row loads (coalesced 256B each) — issue first
        float g[DEGC];
        #pragma unroll
        for (int k = 0; k < DEGC; ++k)
            g[k] = Q[(size_t)arow[k] * DD + lane];
        // P(n) inline — independent of gathers, hides their latency
        const float* f = feat + (size_t)n * DD;
        float p = bias;
        #pragma unroll
        for (int i4 = 0; i4 < 16; ++i4) {
            float4 wv = qa[(i4 << 6) | lane];
            float4 c = *(const float4*)(f + i4 * 4);   // uniform -> broadcast
            p += c.x * wv.x + c.y * wv.y + c.z * wv.z + c.w * wv.w;
        }
        float p0 = (g[0] + g[1]) + (g[2] + g[3]);
        float p1 = (g[4] + g[5]) + (g[6] + g[7]);
        float p2 = (g[8] + g[9]) + (g[10] + g[11]);
        float p3 = (g[12] + g[13]) + (g[14] + g[15]);
        h1[(size_t)a * DD + lane] = tanh_fast(p + ((p0 + p1) + (p2 + p3)));
    }
}

// ---------------------------------------------------------------------------
// K3: hop2 (R6-proven) + flags indirection for h1 rows.
// ---------------------------------------------------------------------------
__global__ __launch_bounds__(256) void hop2_fused(
    const float* __restrict__ feat, const float* __restrict__ h1,
    const int* __restrict__ adj, const int* __restrict__ flags,
    const int* __restrict__ in1, const int* __restrict__ in2,
    const int* __restrict__ neg,
    const float* __restrict__ W2, const float* __restrict__ b2,
    float* __restrict__ out) {

    __shared__ float4 q2[4096];           // 64 KB
    __shared__ float4 cs4[8][16];         // 2 KB

    int tid = threadIdx.x;
    {
        int j = tid & 127, g0 = tid >> 7;
        #pragma unroll
        for (int g = 0; g < 16; ++g) {
            int i4 = g0 * 16 + g;
            q2[(i4 << 7) | j] = *(const float4*)(W2 + j * DD2 + (i4 << 2));
        }
    }

    int lane = tid & 63;
    int w = tid >> 6;
    int r0 = blockIdx.x * 8 + w * 2;
    int r1 = r0 + 1;
    bool a0 = r0 < NROWS, a1 = r1 < NROWS;

    int node0 = 0, node1 = 0;
    #pragma unroll
    for (int m = 0; m < 2; ++m) {
        int r = r0 + m;
        if (r < NROWS) {
            int node = (r < BB) ? in1[r] : (r < 2 * BB ? in2[r - BB] : neg[r - 2 * BB]);
            node = __builtin_amdgcn_readfirstlane(node);
            if (m == 0) node0 = node; else node1 = node;
            const int* arow = adj + node * DEGC;   // uniform
            float s = 0.f;
            #pragma unroll
            for (int k = 0; k < DEGC; ++k) {
                int a = __builtin_amdgcn_readfirstlane(flags[arow[k]]) - 1;
                s += h1[(size_t)a * DD + lane];
            }
            ((float*)&cs4[w * 2 + m][0])[lane] = s;
        }
    }
    __syncthreads();

    const float* cf0 = feat + (size_t)node0 * DD;
    const float* cf1 = feat + (size_t)(a1 ? node1 : node0) * DD;

    float A0 = b2[lane], B0 = b2[DD + lane];
    float A1 = A0, B1 = B0;

    #pragma unroll
    for (int i4 = 0; i4 < 16; ++i4) {
        float4 wA = q2[(i4 << 7) | lane];
        float4 wB = q2[(i4 << 7) | (64 + lane)];
        float4 c0 = *(const float4*)(cf0 + (i4 << 2));
        float4 c1 = *(const float4*)(cf1 + (i4 << 2));
        A0 += c0.x * wA.x + c0.y * wA.y + c0.z * wA.z + c0.w * wA.w;
        B0 += c0.x * wB.x + c0.y * wB.y + c0.z * wB.z + c0.w * wB.w;
        A1 += c1.x * wA.x + c1.y * wA.y + c1.z * wA.z + c1.w * wA.w;
        B1 += c1.x * wB.x + c1.y * wB.y + c1.z * wB.z + c1.w * wB.w;
    }
    #pragma unroll
    for (int i4 = 0; i4 < 16; ++i4) {
        float4 wA = q2[((16 + i4) << 7) | lane];
        float4 wB = q2[((16 + i4) << 7) | (64 + lane)];
        float4 c0 = cs4[w * 2 + 0][i4];
        float4 c1 = cs4[w * 2 + 1][i4];
        A0 += c0.x * wA.x + c0.y * wA.y + c0.z * wA.z + c0.w * wA.w;
        B0 += c0.x * wB.x + c0.y * wB.y + c0.z * wB.z + c0.w * wB.w;
        A1 += c1.x * wA.x + c1.y * wA.y + c1.z * wA.z + c1.w * wA.w;
        B1 += c1.x * wB.x + c1.y * wB.y + c1.z * wB.z + c1.w * wB.w;
    }

    if (a0) {
        float ss = A0 * A0 + B0 * B0;
        #pragma unroll
        for (int off = 32; off > 0; off >>= 1) ss += __shfl_xor(ss, off, 64);
        float inv = 1.0f / fmaxf(sqrtf(ss), 1e-12f);
        out[r0 * DD2 + lane]      = A0 * inv;
        out[r0 * DD2 + DD + lane] = B0 * inv;
    }
    if (a1) {
        float ss = A1 * A1 + B1 * B1;
        #pragma unroll
        for (int off = 32; off > 0; off >>= 1) ss += __shfl_xor(ss, off, 64);
        float inv = 1.0f / fmaxf(sqrtf(ss), 1e-12f);
        out[r1 * DD2 + lane]      = A1 * inv;
        out[r1 * DD2 + DD + lane] = B1 * inv;
    }
}

// ---------------------------------------------------------------------------
extern "C" void kernel_launch(void* const* d_in, const int* in_sizes, int n_in,
                              void* d_out, int out_size, void* d_ws, size_t ws_size,
                              hipStream_t stream) {
    const float* feat = (const float*)d_in[0];
    const int*   adj  = (const int*)d_in[1];
    const int*   in1  = (const int*)d_in[2];
    const int*   in2  = (const int*)d_in[3];
    const int*   neg  = (const int*)d_in[4];
    const float* W1   = (const float*)d_in[5];
    const float* b1   = (const float*)d_in[6];
    const float* W2   = (const float*)d_in[7];
    const float* b2   = (const float*)d_in[8];
    float* out = (float*)d_out;

    // ws layout (~25.3 MB): Q[NN][64] | h1[MAXU][64] | flags[NN] | count | list[MAXU]
    char* p = (char*)d_ws;
    float* Q     = (float*)p;                 size_t off = (size_t)NN * DD * sizeof(float);
    float* h1    = (float*)(p + off);         off += (size_t)MAXU * DD * sizeof(float);
    int*   flags = (int*)(p + off);           off += (size_t)NN * sizeof(int);
    int*   count = (int*)(p + off);           off += 64;
    int*   list  = (int*)(p + off);

    // zero flags + count (contiguous)
    hipMemsetAsync(flags, 0, (size_t)NN * sizeof(int) + 64, stream);

    mark_compact_kernel<<<(NEDGE + 255) / 256, 256, 0, stream>>>(
        adj, in1, in2, neg, flags, list, count);
    qgemm_kernel<<<NN / 16, 256, 0, stream>>>(feat, W1, Q);
    gatherh1_kernel<<<2048, 256, 0, stream>>>(
        feat, Q, adj, list, count, W1, b1, h1);
    hop2_fused<<<(NROWS + 7) / 8, 256, 0, stream>>>(
        feat, h1, adj, flags, in1, in2, neg, W2, b2, out);
}

// Round 11
// 68.265 us; speedup vs baseline: 1.2430x; 1.2430x over previous
//
#include <hip/hip_runtime.h>
#include <math.h>

#define NN   65536
#define DEGC 16
#define DD   64
#define DD2  128
#define BB   1024
#define NEGC 10
#define NROWS (2 * BB + NEGC)      // 2058
#define NEDGE (NROWS * DEGC)       // 32928

__device__ __forceinline__ float tanh_fast(float x) {
    float t = __expf(2.0f * x);
    return 1.0f - 2.0f * __builtin_amdgcn_rcpf(t + 1.0f);
}

// ---------------------------------------------------------------------------
// K1: dense index-free GEMMs for BOTH halves of W1:
//   P[n][j] = sum_i feat[n][i] * W1[j][i]        (self half)
//   Q[n][j] = sum_i feat[n][i] * W1[j][64+i]     (neighbor half)
// R10-proven shape: 4 consecutive nodes/wave, W1 float4-tiled in LDS,
// c-operands via uniform-address broadcast loads, scalar accumulators.
// ---------------------------------------------------------------------------
__global__ __launch_bounds__(256) void pq_gemm_kernel(
    const float* __restrict__ feat, const float* __restrict__ W1,
    float* __restrict__ P, float* __restrict__ Q) {

    __shared__ float4 qa[1024];           // 16 KB: W1[j][4i4..]
    __shared__ float4 qb[1024];           // 16 KB: W1[j][64+4i4..]
    int tid = threadIdx.x;
    {
        int j = tid & 63, g = tid >> 6;
        #pragma unroll
        for (int t = 0; t < 4; ++t) {
            int i4 = g * 4 + t;
            qa[(i4 << 6) | j] = *(const float4*)(W1 + j * DD2 + i4 * 4);
            qb[(i4 << 6) | j] = *(const float4*)(W1 + j * DD2 + DD + i4 * 4);
        }
    }
    __syncthreads();

    int lane = tid & 63;
    int w = tid >> 6;
    int nbase = __builtin_amdgcn_readfirstlane((blockIdx.x * 4 + w) * 4);

    const float* f0 = feat + (size_t)(nbase + 0) * DD;
    const float* f1 = feat + (size_t)(nbase + 1) * DD;
    const float* f2 = feat + (size_t)(nbase + 2) * DD;
    const float* f3 = feat + (size_t)(nbase + 3) * DD;

    float pa0 = 0.f, pa1 = 0.f, pa2 = 0.f, pa3 = 0.f;
    float qb0 = 0.f, qb1 = 0.f, qb2 = 0.f, qb3 = 0.f;
    #pragma unroll
    for (int i4 = 0; i4 < 16; ++i4) {
        float4 wa = qa[(i4 << 6) | lane];          // ds_read_b128
        float4 wb = qb[(i4 << 6) | lane];
        float4 c0 = *(const float4*)(f0 + i4 * 4); // uniform -> broadcast
        float4 c1 = *(const float4*)(f1 + i4 * 4);
        float4 c2 = *(const float4*)(f2 + i4 * 4);
        float4 c3 = *(const float4*)(f3 + i4 * 4);
        pa0 += c0.x * wa.x + c0.y * wa.y + c0.z * wa.z + c0.w * wa.w;
        pa1 += c1.x * wa.x + c1.y * wa.y + c1.z * wa.z + c1.w * wa.w;
        pa2 += c2.x * wa.x + c2.y * wa.y + c2.z * wa.z + c2.w * wa.w;
        pa3 += c3.x * wa.x + c3.y * wa.y + c3.z * wa.z + c3.w * wa.w;
        qb0 += c0.x * wb.x + c0.y * wb.y + c0.z * wb.z + c0.w * wb.w;
        qb1 += c1.x * wb.x + c1.y * wb.y + c1.z * wb.z + c1.w * wb.w;
        qb2 += c2.x * wb.x + c2.y * wb.y + c2.z * wb.z + c2.w * wb.w;
        qb3 += c3.x * wb.x + c3.y * wb.y + c3.z * wb.z + c3.w * wb.w;
    }
    P[(size_t)(nbase + 0) * DD + lane] = pa0;
    P[(size_t)(nbase + 1) * DD + lane] = pa1;
    P[(size_t)(nbase + 2) * DD + lane] = pa2;
    P[(size_t)(nbase + 3) * DD + lane] = pa3;
    Q[(size_t)(nbase + 0) * DD + lane] = qb0;
    Q[(size_t)(nbase + 1) * DD + lane] = qb1;
    Q[(size_t)(nbase + 2) * DD + lane] = qb2;
    Q[(size_t)(nbase + 3) * DD + lane] = qb3;
}

// ---------------------------------------------------------------------------
// K2: per-edge combine — the irreducible scattered traffic, at max occupancy.
//   e=(r,k): n = adj[node_r][k]
//   h1[e][lane] = tanh(P[n][lane] + sum_k2 Q[adj[n][k2]][lane] + b1[lane])
// No LDS, ~45 VGPR -> 8 waves/SIMD; 16 independent 256B gathers per wave.
// ---------------------------------------------------------------------------
__global__ __launch_bounds__(256) void edge_kernel(
    const int* __restrict__ adj,
    const int* __restrict__ in1, const int* __restrict__ in2,
    const int* __restrict__ neg,
    const float* __restrict__ P, const float* __restrict__ Q,
    const float* __restrict__ b1, float* __restrict__ h1) {

    int lane = threadIdx.x & 63;
    int e = blockIdx.x * 4 + (threadIdx.x >> 6);   // grid*4 == NEDGE exactly
    int r = e >> 4, k = e & 15;
    int node = (r < BB) ? in1[r] : (r < 2 * BB ? in2[r - BB] : neg[r - 2 * BB]);
    node = __builtin_amdgcn_readfirstlane(node);
    int n = __builtin_amdgcn_readfirstlane(adj[node * DEGC + k]);
    const int* arow = adj + n * DEGC;              // uniform -> s_load_dwordx16

    float g[DEGC];
    #pragma unroll
    for (int k2 = 0; k2 < DEGC; ++k2)
        g[k2] = Q[(size_t)arow[k2] * DD + lane];   // 16 independent 256B loads
    float p = P[(size_t)n * DD + lane] + b1[lane]; // coalesced row reads

    float p0 = (g[0] + g[1]) + (g[2] + g[3]);
    float p1 = (g[4] + g[5]) + (g[6] + g[7]);
    float p2 = (g[8] + g[9]) + (g[10] + g[11]);
    float p3 = (g[12] + g[13]) + (g[14] + g[15]);
    h1[(size_t)e * DD + lane] = tanh_fast(p + ((p0 + p1) + (p2 + p3)));
}

// ---------------------------------------------------------------------------
// K3: fused sum16 + GEMV2 + normalize (R6-proven, unchanged).
// ---------------------------------------------------------------------------
__global__ __launch_bounds__(256) void hop2_fused(
    const float* __restrict__ feat, const float* __restrict__ h1,
    const int* __restrict__ in1, const int* __restrict__ in2,
    const int* __restrict__ neg,
    const float* __restrict__ W2, const float* __restrict__ b2,
    float* __restrict__ out) {

    __shared__ float4 q2[4096];           // 64 KB
    __shared__ float4 cs4[8][16];         // 2 KB

    int tid = threadIdx.x;
    {
        int j = tid & 127, g0 = tid >> 7;
        #pragma unroll
        for (int g = 0; g < 16; ++g) {
            int i4 = g0 * 16 + g;
            q2[(i4 << 7) | j] = *(const float4*)(W2 + j * DD2 + (i4 << 2));
        }
    }

    int lane = tid & 63;
    int w = tid >> 6;
    int r0 = blockIdx.x * 8 + w * 2;
    int r1 = r0 + 1;
    bool a0 = r0 < NROWS, a1 = r1 < NROWS;

    #pragma unroll
    for (int m = 0; m < 2; ++m) {
        int r = r0 + m;
        if (r < NROWS) {
            const float* base = h1 + (size_t)r * DEGC * DD;
            float s = 0.f;
            #pragma unroll
            for (int k = 0; k < DEGC; ++k)
                s += base[k * DD + lane];
            ((float*)&cs4[w * 2 + m][0])[lane] = s;
        }
    }
    __syncthreads();

    int node0 = a0 ? ((r0 < BB) ? in1[r0] : (r0 < 2 * BB ? in2[r0 - BB] : neg[r0 - 2 * BB])) : 0;
    int node1 = a1 ? ((r1 < BB) ? in1[r1] : (r1 < 2 * BB ? in2[r1 - BB] : neg[r1 - 2 * BB])) : node0;
    node0 = __builtin_amdgcn_readfirstlane(node0);
    node1 = __builtin_amdgcn_readfirstlane(node1);
    const float* cf0 = feat + (size_t)node0 * DD;
    const float* cf1 = feat + (size_t)node1 * DD;

    float A0 = b2[lane], B0 = b2[DD + lane];
    float A1 = A0, B1 = B0;

    #pragma unroll
    for (int i4 = 0; i4 < 16; ++i4) {
        float4 wA = q2[(i4 << 7) | lane];
        float4 wB = q2[(i4 << 7) | (64 + lane)];
        float4 c0 = *(const float4*)(cf0 + (i4 << 2));
        float4 c1 = *(const float4*)(cf1 + (i4 << 2));
        A0 += c0.x * wA.x + c0.y * wA.y + c0.z * wA.z + c0.w * wA.w;
        B0 += c0.x * wB.x + c0.y * wB.y + c0.z * wB.z + c0.w * wB.w;
        A1 += c1.x * wA.x + c1.y * wA.y + c1.z * wA.z + c1.w * wA.w;
        B1 += c1.x * wB.x + c1.y * wB.y + c1.z * wB.z + c1.w * wB.w;
    }
    #pragma unroll
    for (int i4 = 0; i4 < 16; ++i4) {
        float4 wA = q2[((16 + i4) << 7) | lane];
        float4 wB = q2[((16 + i4) << 7) | (64 + lane)];
        float4 c0 = cs4[w * 2 + 0][i4];
        float4 c1 = cs4[w * 2 + 1][i4];
        A0 += c0.x * wA.x + c0.y * wA.y + c0.z * wA.z + c0.w * wA.w;
        B0 += c0.x * wB.x + c0.y * wB.y + c0.z * wB.z + c0.w * wB.w;
        A1 += c1.x * wA.x + c1.y * wA.y + c1.z * wA.z + c1.w * wA.w;
        B1 += c1.x * wB.x + c1.y * wB.y + c1.z * wB.z + c1.w * wB.w;
    }

    if (a0) {
        float ss = A0 * A0 + B0 * B0;
        #pragma unroll
        for (int off = 32; off > 0; off >>= 1) ss += __shfl_xor(ss, off, 64);
        float inv = 1.0f / fmaxf(sqrtf(ss), 1e-12f);
        out[r0 * DD2 + lane]      = A0 * inv;
        out[r0 * DD2 + DD + lane] = B0 * inv;
    }
    if (a1) {
        float ss = A1 * A1 + B1 * B1;
        #pragma unroll
        for (int off = 32; off > 0; off >>= 1) ss += __shfl_xor(ss, off, 64);
        float inv = 1.0f / fmaxf(sqrtf(ss), 1e-12f);
        out[r1 * DD2 + lane]      = A1 * inv;
        out[r1 * DD2 + DD + lane] = B1 * inv;
    }
}

// ---------------------------------------------------------------------------
extern "C" void kernel_launch(void* const* d_in, const int* in_sizes, int n_in,
                              void* d_out, int out_size, void* d_ws, size_t ws_size,
                              hipStream_t stream) {
    const float* feat = (const float*)d_in[0];
    const int*   adj  = (const int*)d_in[1];
    const int*   in1  = (const int*)d_in[2];
    const int*   in2  = (const int*)d_in[3];
    const int*   neg  = (const int*)d_in[4];
    const float* W1   = (const float*)d_in[5];
    const float* b1   = (const float*)d_in[6];
    const float* W2   = (const float*)d_in[7];
    const float* b2   = (const float*)d_in[8];
    float* out = (float*)d_out;

    // ws layout (~42 MB): P[NN][64] | Q[NN][64] | h1[NEDGE][64]
    char* p = (char*)d_ws;
    float* P  = (float*)p;                  size_t off = (size_t)NN * DD * sizeof(float);
    float* Q  = (float*)(p + off);          off += (size_t)NN * DD * sizeof(float);
    float* h1 = (float*)(p + off);

    pq_gemm_kernel<<<NN / 16, 256, 0, stream>>>(feat, W1, P, Q);
    edge_kernel<<<NEDGE / 4, 256, 0, stream>>>(adj, in1, in2, neg, P, Q, b1, h1);
    hop2_fused<<<(NROWS + 7) / 8, 256, 0, stream>>>(
        feat, h1, in1, in2, neg, W2, b2, out);
}

// Round 12
// 60.496 us; speedup vs baseline: 1.4026x; 1.1284x over previous
//
#include <hip/hip_runtime.h>
#include <math.h>

#define NN   65536
#define DEGC 16
#define DD   64
#define DD2  128
#define BB   1024
#define NEGC 10
#define NROWS (2 * BB + NEGC)      // 2058
#define NEDGE (NROWS * DEGC)       // 32928

__device__ __forceinline__ float tanh_fast(float x) {
    float t = __expf(2.0f * x);
    return 1.0f - 2.0f * __builtin_amdgcn_rcpf(t + 1.0f);
}

__device__ __forceinline__ unsigned short f2bf(float v) {   // RNE bf16 pack
    unsigned int x = __float_as_uint(v);
    x += 0x7FFFu + ((x >> 16) & 1u);
    return (unsigned short)(x >> 16);
}
__device__ __forceinline__ float bf2f(unsigned short u) {
    return __uint_as_float(((unsigned int)u) << 16);
}

// ---------------------------------------------------------------------------
// K1: dense index-free GEMMs, bf16 outputs:
//   Pb[n][j] = bf16( feat[n]@W1a[j] + b1[j] )   (self half, bias folded)
//   Qb[n][j] = bf16( feat[n]@W1b[j] )           (neighbor half)
// R11-proven shape: 4 nodes/wave, W1 float4-tiled LDS, uniform-broadcast c.
// ---------------------------------------------------------------------------
__global__ __launch_bounds__(256) void pq_gemm_kernel(
    const float* __restrict__ feat, const float* __restrict__ W1,
    const float* __restrict__ b1,
    unsigned short* __restrict__ Pb, unsigned short* __restrict__ Qb) {

    __shared__ float4 qa[1024];           // 16 KB: W1[j][4i4..]
    __shared__ float4 qb[1024];           // 16 KB: W1[j][64+4i4..]
    int tid = threadIdx.x;
    {
        int j = tid & 63, g = tid >> 6;
        #pragma unroll
        for (int t = 0; t < 4; ++t) {
            int i4 = g * 4 + t;
            qa[(i4 << 6) | j] = *(const float4*)(W1 + j * DD2 + i4 * 4);
            qb[(i4 << 6) | j] = *(const float4*)(W1 + j * DD2 + DD + i4 * 4);
        }
    }
    __syncthreads();

    int lane = tid & 63;
    int w = tid >> 6;
    int nbase = __builtin_amdgcn_readfirstlane((blockIdx.x * 4 + w) * 4);

    const float* f0 = feat + (size_t)(nbase + 0) * DD;
    const float* f1 = feat + (size_t)(nbase + 1) * DD;
    const float* f2 = feat + (size_t)(nbase + 2) * DD;
    const float* f3 = feat + (size_t)(nbase + 3) * DD;

    float bias = b1[lane];
    float pa0 = bias, pa1 = bias, pa2 = bias, pa3 = bias;
    float qv0 = 0.f, qv1 = 0.f, qv2 = 0.f, qv3 = 0.f;
    #pragma unroll
    for (int i4 = 0; i4 < 16; ++i4) {
        float4 wa = qa[(i4 << 6) | lane];          // ds_read_b128
        float4 wb = qb[(i4 << 6) | lane];
        float4 c0 = *(const float4*)(f0 + i4 * 4); // uniform -> broadcast
        float4 c1 = *(const float4*)(f1 + i4 * 4);
        float4 c2 = *(const float4*)(f2 + i4 * 4);
        float4 c3 = *(const float4*)(f3 + i4 * 4);
        pa0 += c0.x * wa.x + c0.y * wa.y + c0.z * wa.z + c0.w * wa.w;
        pa1 += c1.x * wa.x + c1.y * wa.y + c1.z * wa.z + c1.w * wa.w;
        pa2 += c2.x * wa.x + c2.y * wa.y + c2.z * wa.z + c2.w * wa.w;
        pa3 += c3.x * wa.x + c3.y * wa.y + c3.z * wa.z + c3.w * wa.w;
        qv0 += c0.x * wb.x + c0.y * wb.y + c0.z * wb.z + c0.w * wb.w;
        qv1 += c1.x * wb.x + c1.y * wb.y + c1.z * wb.z + c1.w * wb.w;
        qv2 += c2.x * wb.x + c2.y * wb.y + c2.z * wb.z + c2.w * wb.w;
        qv3 += c3.x * wb.x + c3.y * wb.y + c3.z * wb.z + c3.w * wb.w;
    }
    Pb[(size_t)(nbase + 0) * DD + lane] = f2bf(pa0);
    Pb[(size_t)(nbase + 1) * DD + lane] = f2bf(pa1);
    Pb[(size_t)(nbase + 2) * DD + lane] = f2bf(pa2);
    Pb[(size_t)(nbase + 3) * DD + lane] = f2bf(pa3);
    Qb[(size_t)(nbase + 0) * DD + lane] = f2bf(qv0);
    Qb[(size_t)(nbase + 1) * DD + lane] = f2bf(qv1);
    Qb[(size_t)(nbase + 2) * DD + lane] = f2bf(qv2);
    Qb[(size_t)(nbase + 3) * DD + lane] = f2bf(qv3);
}

// ---------------------------------------------------------------------------
// K2: per-edge combine — scattered gather now reads 128B bf16 rows (2 cache
// lines instead of 4): halves the L2-miss volume that bounds this kernel.
//   h1[e][lane] = tanh( Pb[n][lane] + sum_k2 Qb[adj[n][k2]][lane] )
// ---------------------------------------------------------------------------
__global__ __launch_bounds__(256) void edge_kernel(
    const int* __restrict__ adj,
    const int* __restrict__ in1, const int* __restrict__ in2,
    const int* __restrict__ neg,
    const unsigned short* __restrict__ Pb, const unsigned short* __restrict__ Qb,
    float* __restrict__ h1) {

    int lane = threadIdx.x & 63;
    int e = blockIdx.x * 4 + (threadIdx.x >> 6);   // grid*4 == NEDGE exactly
    int r = e >> 4, k = e & 15;
    int node = (r < BB) ? in1[r] : (r < 2 * BB ? in2[r - BB] : neg[r - 2 * BB]);
    node = __builtin_amdgcn_readfirstlane(node);
    int n = __builtin_amdgcn_readfirstlane(adj[node * DEGC + k]);
    const int* arow = adj + n * DEGC;              // uniform -> s_load_dwordx16

    float g[DEGC];
    #pragma unroll
    for (int k2 = 0; k2 < DEGC; ++k2)
        g[k2] = bf2f(Qb[(size_t)arow[k2] * DD + lane]);  // 16 x 128B requests
    float p = bf2f(Pb[(size_t)n * DD + lane]);

    float p0 = (g[0] + g[1]) + (g[2] + g[3]);
    float p1 = (g[4] + g[5]) + (g[6] + g[7]);
    float p2 = (g[8] + g[9]) + (g[10] + g[11]);
    float p3 = (g[12] + g[13]) + (g[14] + g[15]);
    h1[(size_t)e * DD + lane] = tanh_fast(p + ((p0 + p1) + (p2 + p3)));
}

// ---------------------------------------------------------------------------
// K3: fused sum16 + GEMV2 + normalize (R6-proven, unchanged).
// ---------------------------------------------------------------------------
__global__ __launch_bounds__(256) void hop2_fused(
    const float* __restrict__ feat, const float* __restrict__ h1,
    const int* __restrict__ in1, const int* __restrict__ in2,
    const int* __restrict__ neg,
    const float* __restrict__ W2, const float* __restrict__ b2,
    float* __restrict__ out) {

    __shared__ float4 q2[4096];           // 64 KB
    __shared__ float4 cs4[8][16];         // 2 KB

    int tid = threadIdx.x;
    {
        int j = tid & 127, g0 = tid >> 7;
        #pragma unroll
        for (int g = 0; g < 16; ++g) {
            int i4 = g0 * 16 + g;
            q2[(i4 << 7) | j] = *(const float4*)(W2 + j * DD2 + (i4 << 2));
        }
    }

    int lane = tid & 63;
    int w = tid >> 6;
    int r0 = blockIdx.x * 8 + w * 2;
    int r1 = r0 + 1;
    bool a0 = r0 < NROWS, a1 = r1 < NROWS;

    #pragma unroll
    for (int m = 0; m < 2; ++m) {
        int r = r0 + m;
        if (r < NROWS) {
            const float* base = h1 + (size_t)r * DEGC * DD;
            float s = 0.f;
            #pragma unroll
            for (int k = 0; k < DEGC; ++k)
                s += base[k * DD + lane];
            ((float*)&cs4[w * 2 + m][0])[lane] = s;
        }
    }
    __syncthreads();

    int node0 = a0 ? ((r0 < BB) ? in1[r0] : (r0 < 2 * BB ? in2[r0 - BB] : neg[r0 - 2 * BB])) : 0;
    int node1 = a1 ? ((r1 < BB) ? in1[r1] : (r1 < 2 * BB ? in2[r1 - BB] : neg[r1 - 2 * BB])) : node0;
    node0 = __builtin_amdgcn_readfirstlane(node0);
    node1 = __builtin_amdgcn_readfirstlane(node1);
    const float* cf0 = feat + (size_t)node0 * DD;
    const float* cf1 = feat + (size_t)node1 * DD;

    float A0 = b2[lane], B0 = b2[DD + lane];
    float A1 = A0, B1 = B0;

    #pragma unroll
    for (int i4 = 0; i4 < 16; ++i4) {
        float4 wA = q2[(i4 << 7) | lane];
        float4 wB = q2[(i4 << 7) | (64 + lane)];
        float4 c0 = *(const float4*)(cf0 + (i4 << 2));
        float4 c1 = *(const float4*)(cf1 + (i4 << 2));
        A0 += c0.x * wA.x + c0.y * wA.y + c0.z * wA.z + c0.w * wA.w;
        B0 += c0.x * wB.x + c0.y * wB.y + c0.z * wB.z + c0.w * wB.w;
        A1 += c1.x * wA.x + c1.y * wA.y + c1.z * wA.z + c1.w * wA.w;
        B1 += c1.x * wB.x + c1.y * wB.y + c1.z * wB.z + c1.w * wB.w;
    }
    #pragma unroll
    for (int i4 = 0; i4 < 16; ++i4) {
        float4 wA = q2[((16 + i4) << 7) | lane];
        float4 wB = q2[((16 + i4) << 7) | (64 + lane)];
        float4 c0 = cs4[w * 2 + 0][i4];
        float4 c1 = cs4[w * 2 + 1][i4];
        A0 += c0.x * wA.x + c0.y * wA.y + c0.z * wA.z + c0.w * wA.w;
        B0 += c0.x * wB.x + c0.y * wB.y + c0.z * wB.z + c0.w * wB.w;
        A1 += c1.x * wA.x + c1.y * wA.y + c1.z * wA.z + c1.w * wA.w;
        B1 += c1.x * wB.x + c1.y * wB.y + c1.z * wB.z + c1.w * wB.w;
    }

    if (a0) {
        float ss = A0 * A0 + B0 * B0;
        #pragma unroll
        for (int off = 32; off > 0; off >>= 1) ss += __shfl_xor(ss, off, 64);
        float inv = 1.0f / fmaxf(sqrtf(ss), 1e-12f);
        out[r0 * DD2 + lane]      = A0 * inv;
        out[r0 * DD2 + DD + lane] = B0 * inv;
    }
    if (a1) {
        float ss = A1 * A1 + B1 * B1;
        #pragma unroll
        for (int off = 32; off > 0; off >>= 1) ss += __shfl_xor(ss, off, 64);
        float inv = 1.0f / fmaxf(sqrtf(ss), 1e-12f);
        out[r1 * DD2 + lane]      = A1 * inv;
        out[r1 * DD2 + DD + lane] = B1 * inv;
    }
}

// ---------------------------------------------------------------------------
extern "C" void kernel_launch(void* const* d_in, const int* in_sizes, int n_in,
                              void* d_out, int out_size, void* d_ws, size_t ws_size,
                              hipStream_t stream) {
    const float* feat = (const float*)d_in[0];
    const int*   adj  = (const int*)d_in[1];
    const int*   in1  = (const int*)d_in[2];
    const int*   in2  = (const int*)d_in[3];
    const int*   neg  = (const int*)d_in[4];
    const float* W1   = (const float*)d_in[5];
    const float* b1   = (const float*)d_in[6];
    const float* W2   = (const float*)d_in[7];
    const float* b2   = (const float*)d_in[8];
    float* out = (float*)d_out;

    // ws layout (~25.2 MB): Pb[NN][64] bf16 | Qb[NN][64] bf16 | h1[NEDGE][64] f32
    char* p = (char*)d_ws;
    unsigned short* Pb = (unsigned short*)p;   size_t off = (size_t)NN * DD * sizeof(unsigned short);
    unsigned short* Qb = (unsigned short*)(p + off); off += (size_t)NN * DD * sizeof(unsigned short);
    float* h1 = (float*)(p + off);

    pq_gemm_kernel<<<NN / 16, 256, 0, stream>>>(feat, W1, b1, Pb, Qb);
    edge_kernel<<<NEDGE / 4, 256, 0, stream>>>(adj, in1, in2, neg, Pb, Qb, h1);
    hop2_fused<<<(NROWS + 7) / 8, 256, 0, stream>>>(
        feat, h1, in1, in2, neg, W2, b2, out);
}

// Round 13
// 59.332 us; speedup vs baseline: 1.4301x; 1.0196x over previous
//
#include <hip/hip_runtime.h>
#include <math.h>

#define NN   65536
#define DEGC 16
#define DD   64
#define DD2  128
#define BB   1024
#define NEGC 10
#define NROWS (2 * BB + NEGC)      // 2058
#define NEDGE (NROWS * DEGC)       // 32928

__device__ __forceinline__ float tanh_fast(float x) {
    float t = __expf(2.0f * x);
    return 1.0f - 2.0f * __builtin_amdgcn_rcpf(t + 1.0f);
}

__device__ __forceinline__ unsigned short f2bf(float v) {   // RNE bf16 pack
    unsigned int x = __float_as_uint(v);
    x += 0x7FFFu + ((x >> 16) & 1u);
    return (unsigned short)(x >> 16);
}
__device__ __forceinline__ float bf2f(unsigned short u) {
    return __uint_as_float(((unsigned int)u) << 16);
}

// ---------------------------------------------------------------------------
// K1: dense index-free GEMMs, bf16 outputs (R12-proven, unchanged):
//   Pb[n][j] = bf16( feat[n]@W1a[j] + b1[j] );  Qb[n][j] = bf16( feat[n]@W1b[j] )
// ---------------------------------------------------------------------------
__global__ __launch_bounds__(256) void pq_gemm_kernel(
    const float* __restrict__ feat, const float* __restrict__ W1,
    const float* __restrict__ b1,
    unsigned short* __restrict__ Pb, unsigned short* __restrict__ Qb) {

    __shared__ float4 qa[1024];           // 16 KB: W1[j][4i4..]
    __shared__ float4 qb[1024];           // 16 KB: W1[j][64+4i4..]
    int tid = threadIdx.x;
    {
        int j = tid & 63, g = tid >> 6;
        #pragma unroll
        for (int t = 0; t < 4; ++t) {
            int i4 = g * 4 + t;
            qa[(i4 << 6) | j] = *(const float4*)(W1 + j * DD2 + i4 * 4);
            qb[(i4 << 6) | j] = *(const float4*)(W1 + j * DD2 + DD + i4 * 4);
        }
    }
    __syncthreads();

    int lane = tid & 63;
    int w = tid >> 6;
    int nbase = __builtin_amdgcn_readfirstlane((blockIdx.x * 4 + w) * 4);

    const float* f0 = feat + (size_t)(nbase + 0) * DD;
    const float* f1 = feat + (size_t)(nbase + 1) * DD;
    const float* f2 = feat + (size_t)(nbase + 2) * DD;
    const float* f3 = feat + (size_t)(nbase + 3) * DD;

    float bias = b1[lane];
    float pa0 = bias, pa1 = bias, pa2 = bias, pa3 = bias;
    float qv0 = 0.f, qv1 = 0.f, qv2 = 0.f, qv3 = 0.f;
    #pragma unroll
    for (int i4 = 0; i4 < 16; ++i4) {
        float4 wa = qa[(i4 << 6) | lane];          // ds_read_b128
        float4 wb = qb[(i4 << 6) | lane];
        float4 c0 = *(const float4*)(f0 + i4 * 4); // uniform -> broadcast
        float4 c1 = *(const float4*)(f1 + i4 * 4);
        float4 c2 = *(const float4*)(f2 + i4 * 4);
        float4 c3 = *(const float4*)(f3 + i4 * 4);
        pa0 += c0.x * wa.x + c0.y * wa.y + c0.z * wa.z + c0.w * wa.w;
        pa1 += c1.x * wa.x + c1.y * wa.y + c1.z * wa.z + c1.w * wa.w;
        pa2 += c2.x * wa.x + c2.y * wa.y + c2.z * wa.z + c2.w * wa.w;
        pa3 += c3.x * wa.x + c3.y * wa.y + c3.z * wa.z + c3.w * wa.w;
        qv0 += c0.x * wb.x + c0.y * wb.y + c0.z * wb.z + c0.w * wb.w;
        qv1 += c1.x * wb.x + c1.y * wb.y + c1.z * wb.z + c1.w * wb.w;
        qv2 += c2.x * wb.x + c2.y * wb.y + c2.z * wb.z + c2.w * wb.w;
        qv3 += c3.x * wb.x + c3.y * wb.y + c3.z * wb.z + c3.w * wb.w;
    }
    Pb[(size_t)(nbase + 0) * DD + lane] = f2bf(pa0);
    Pb[(size_t)(nbase + 1) * DD + lane] = f2bf(pa1);
    Pb[(size_t)(nbase + 2) * DD + lane] = f2bf(pa2);
    Pb[(size_t)(nbase + 3) * DD + lane] = f2bf(pa3);
    Qb[(size_t)(nbase + 0) * DD + lane] = f2bf(qv0);
    Qb[(size_t)(nbase + 1) * DD + lane] = f2bf(qv1);
    Qb[(size_t)(nbase + 2) * DD + lane] = f2bf(qv2);
    Qb[(size_t)(nbase + 3) * DD + lane] = f2bf(qv3);
}

// ---------------------------------------------------------------------------
// K2: per-edge combine, request-widened: 4 edges/wave, 8B/lane gathers.
// Wave's 4 edges = 4 consecutive neighbors of ONE graph row (never crosses).
// 16-lane group g owns edge g; lane (g,q) owns j = 4q..4q+3.
// Per gather instruction: 4 rows x 128B = 512B (vs 128B before) ->
// ~4.5 VMEM requests/edge instead of 17, same line traffic.
//   h1[e][j] = tanh( Pb[n_e][j] + sum_i Qb[nbr_i][j] )
// ---------------------------------------------------------------------------
__global__ __launch_bounds__(256) void edge_kernel(
    const int* __restrict__ adj,
    const int* __restrict__ in1, const int* __restrict__ in2,
    const int* __restrict__ neg,
    const unsigned short* __restrict__ Pb, const unsigned short* __restrict__ Qb,
    float* __restrict__ h1) {

    int tid = threadIdx.x;
    int lane = tid & 63;
    int g = lane >> 4;                    // edge slot 0..3
    int q = lane & 15;                    // j-slice: j = 4q..4q+3
    int wid = blockIdx.x * 4 + (tid >> 6);
    int ebase = wid * 4;                  // 4 consecutive edges, same graph row
    int r = ebase >> 4;                   // uniform per wave
    int kbase = ebase & 15;               // 0,4,8,12

    int node = (r < BB) ? in1[r] : (r < 2 * BB ? in2[r - BB] : neg[r - 2 * BB]);
    node = __builtin_amdgcn_readfirstlane(node);
    const int* arow = adj + node * DEGC + kbase;   // uniform -> s_loads
    int n0 = __builtin_amdgcn_readfirstlane(arow[0]);
    int n1 = __builtin_amdgcn_readfirstlane(arow[1]);
    int n2 = __builtin_amdgcn_readfirstlane(arow[2]);
    int n3 = __builtin_amdgcn_readfirstlane(arow[3]);
    int n_g = (g == 0) ? n0 : (g == 1) ? n1 : (g == 2) ? n2 : n3;

    // Each lane holds one neighbor id of its group's edge: nbr = adj[n_g][q]
    int nbr = adj[(size_t)n_g * DEGC + q];

    // Self-term first (independent request, issues early)
    float a0, a1, a2, a3;
    {
        unsigned long long v = *(const unsigned long long*)(Pb + (size_t)n_g * DD + q * 4);
        a0 = bf2f((unsigned short)(v));
        a1 = bf2f((unsigned short)(v >> 16));
        a2 = bf2f((unsigned short)(v >> 32));
        a3 = bf2f((unsigned short)(v >> 48));
    }

    // 16 gather instructions, each pulls 4 rows (512B) across the wave.
    #pragma unroll
    for (int i = 0; i < DEGC; ++i) {
        int row = __shfl(nbr, g * 16 + i, 64);     // ds_bpermute broadcast
        unsigned long long v = *(const unsigned long long*)(Qb + (size_t)row * DD + q * 4);
        a0 += bf2f((unsigned short)(v));
        a1 += bf2f((unsigned short)(v >> 16));
        a2 += bf2f((unsigned short)(v >> 32));
        a3 += bf2f((unsigned short)(v >> 48));
    }

    float4 o;
    o.x = tanh_fast(a0);
    o.y = tanh_fast(a1);
    o.z = tanh_fast(a2);
    o.w = tanh_fast(a3);
    // 64 lanes x 16B = 1KB contiguous (4 consecutive h1 rows) — fully coalesced
    *(float4*)(h1 + (size_t)(ebase + g) * DD + q * 4) = o;
}

// ---------------------------------------------------------------------------
// K3: fused sum16 + GEMV2 + normalize (R6-proven, unchanged).
// ---------------------------------------------------------------------------
__global__ __launch_bounds__(256) void hop2_fused(
    const float* __restrict__ feat, const float* __restrict__ h1,
    const int* __restrict__ in1, const int* __restrict__ in2,
    const int* __restrict__ neg,
    const float* __restrict__ W2, const float* __restrict__ b2,
    float* __restrict__ out) {

    __shared__ float4 q2[4096];           // 64 KB
    __shared__ float4 cs4[8][16];         // 2 KB

    int tid = threadIdx.x;
    {
        int j = tid & 127, g0 = tid >> 7;
        #pragma unroll
        for (int g = 0; g < 16; ++g) {
            int i4 = g0 * 16 + g;
            q2[(i4 << 7) | j] = *(const float4*)(W2 + j * DD2 + (i4 << 2));
        }
    }

    int lane = tid & 63;
    int w = tid >> 6;
    int r0 = blockIdx.x * 8 + w * 2;
    int r1 = r0 + 1;
    bool a0 = r0 < NROWS, a1 = r1 < NROWS;

    #pragma unroll
    for (int m = 0; m < 2; ++m) {
        int r = r0 + m;
        if (r < NROWS) {
            const float* base = h1 + (size_t)r * DEGC * DD;
            float s = 0.f;
            #pragma unroll
            for (int k = 0; k < DEGC; ++k)
                s += base[k * DD + lane];
            ((float*)&cs4[w * 2 + m][0])[lane] = s;
        }
    }
    __syncthreads();

    int node0 = a0 ? ((r0 < BB) ? in1[r0] : (r0 < 2 * BB ? in2[r0 - BB] : neg[r0 - 2 * BB])) : 0;
    int node1 = a1 ? ((r1 < BB) ? in1[r1] : (r1 < 2 * BB ? in2[r1 - BB] : neg[r1 - 2 * BB])) : node0;
    node0 = __builtin_amdgcn_readfirstlane(node0);
    node1 = __builtin_amdgcn_readfirstlane(node1);
    const float* cf0 = feat + (size_t)node0 * DD;
    const float* cf1 = feat + (size_t)node1 * DD;

    float A0 = b2[lane], B0 = b2[DD + lane];
    float A1 = A0, B1 = B0;

    #pragma unroll
    for (int i4 = 0; i4 < 16; ++i4) {
        float4 wA = q2[(i4 << 7) | lane];
        float4 wB = q2[(i4 << 7) | (64 + lane)];
        float4 c0 = *(const float4*)(cf0 + (i4 << 2));
        float4 c1 = *(const float4*)(cf1 + (i4 << 2));
        A0 += c0.x * wA.x + c0.y * wA.y + c0.z * wA.z + c0.w * wA.w;
        B0 += c0.x * wB.x + c0.y * wB.y + c0.z * wB.z + c0.w * wB.w;
        A1 += c1.x * wA.x + c1.y * wA.y + c1.z * wA.z + c1.w * wA.w;
        B1 += c1.x * wB.x + c1.y * wB.y + c1.z * wB.z + c1.w * wB.w;
    }
    #pragma unroll
    for (int i4 = 0; i4 < 16; ++i4) {
        float4 wA = q2[((16 + i4) << 7) | lane];
        float4 wB = q2[((16 + i4) << 7) | (64 + lane)];
        float4 c0 = cs4[w * 2 + 0][i4];
        float4 c1 = cs4[w * 2 + 1][i4];
        A0 += c0.x * wA.x + c0.y * wA.y + c0.z * wA.z + c0.w * wA.w;
        B0 += c0.x * wB.x + c0.y * wB.y + c0.z * wB.z + c0.w * wB.w;
        A1 += c1.x * wA.x + c1.y * wA.y + c1.z * wA.z + c1.w * wA.w;
        B1 += c1.x * wB.x + c1.y * wB.y + c1.z * wB.z + c1.w * wB.w;
    }

    if (a0) {
        float ss = A0 * A0 + B0 * B0;
        #pragma unroll
        for (int off = 32; off > 0; off >>= 1) ss += __shfl_xor(ss, off, 64);
        float inv = 1.0f / fmaxf(sqrtf(ss), 1e-12f);
        out[r0 * DD2 + lane]      = A0 * inv;
        out[r0 * DD2 + DD + lane] = B0 * inv;
    }
    if (a1) {
        float ss = A1 * A1 + B1 * B1;
        #pragma unroll
        for (int off = 32; off > 0; off >>= 1) ss += __shfl_xor(ss, off, 64);
        float inv = 1.0f / fmaxf(sqrtf(ss), 1e-12f);
        out[r1 * DD2 + lane]      = A1 * inv;
        out[r1 * DD2 + DD + lane] = B1 * inv;
    }
}

// ---------------------------------------------------------------------------
extern "C" void kernel_launch(void* const* d_in, const int* in_sizes, int n_in,
                              void* d_out, int out_size, void* d_ws, size_t ws_size,
                              hipStream_t stream) {
    const float* feat = (const float*)d_in[0];
    const int*   adj  = (const int*)d_in[1];
    const int*   in1  = (const int*)d_in[2];
    const int*   in2  = (const int*)d_in[3];
    const int*   neg  = (const int*)d_in[4];
    const float* W1   = (const float*)d_in[5];
    const float* b1   = (const float*)d_in[6];
    const float* W2   = (const float*)d_in[7];
    const float* b2   = (const float*)d_in[8];
    float* out = (float*)d_out;

    // ws layout (~25.2 MB): Pb[NN][64] bf16 | Qb[NN][64] bf16 | h1[NEDGE][64] f32
    char* p = (char*)d_ws;
    unsigned short* Pb = (unsigned short*)p;   size_t off = (size_t)NN * DD * sizeof(unsigned short);
    unsigned short* Qb = (unsigned short*)(p + off); off += (size_t)NN * DD * sizeof(unsigned short);
    float* h1 = (float*)(p + off);

    pq_gemm_kernel<<<NN / 16, 256, 0, stream>>>(feat, W1, b1, Pb, Qb);
    edge_kernel<<<NEDGE / 16, 256, 0, stream>>>(adj, in1, in2, neg, Pb, Qb, h1);
    hop2_fused<<<(NROWS + 7) / 8, 256, 0, stream>>>(
        feat, h1, in1, in2, neg, W2, b2, out);
}